// Round 1
// baseline (4241.030 us; speedup 1.0000x reference)
//
#include <hip/hip_runtime.h>
#include <hip/hip_bf16.h>
#include <math.h>

#define EMBED 256
#define ACTD  7
#define MEM   200
#define STOCH 30
#define HIDD  200
#define T_    256
#define B_    512
#define EAIN  263      // EMBED + ACTD
#define G3    600      // 3*MEM

// ---------- math helpers ----------
__device__ __forceinline__ float eluf(float x)  { return x > 0.f ? x : expm1f(x); }
__device__ __forceinline__ float sigmf(float x) { return 1.f / (1.f + __expf(-x)); }
__device__ __forceinline__ float splusf(float x){ return fmaxf(x, 0.f) + log1pf(__expf(-fabsf(x))); }

// ---------- reset dtype detection ----------
// mode 0: int32 (only bytes at idx%4==0 nonzero)
// mode 1: u8/bool (nonzero odd bytes, all values <=1)
// mode 2: f32 (bytes > 1 present)
__global__ void detect_kernel(const unsigned char* __restrict__ p, int n, int* __restrict__ flags)
{
    __shared__ int s_mis, s_gt1;
    if (threadIdx.x == 0) { s_mis = 0; s_gt1 = 0; }
    __syncthreads();
    int mis = 0, gt1 = 0;
    for (int i = threadIdx.x; i < n; i += blockDim.x) {
        unsigned char v = p[i];
        if (v) {
            if (i & 3) mis = 1;
            if (v > 1) gt1 = 1;
        }
    }
    if (mis) atomicOr(&s_mis, 1);
    if (gt1) atomicOr(&s_gt1, 1);
    __syncthreads();
    if (threadIdx.x == 0) flags[0] = s_mis ? (s_gt1 ? 2 : 1) : 0;
}

__device__ __forceinline__ bool resetval(const unsigned char* __restrict__ p, int mode, int idx)
{
    if (mode == 0) return ((const int*)p)[idx] != 0;
    if (mode == 1) return p[idx] != 0;
    return ((const float*)p)[idx] != 0.f;
}

// ---------- phase A: gi = elu([e,a]@W_ea+b_ea)@W_ih + b_ih  (parallel over rows) ----------
#define GI_ROWS 32
#define GI_THREADS 640

__global__ __launch_bounds__(GI_THREADS, 1)
void gi_kernel(const float* __restrict__ embed, const float* __restrict__ action,
               const float* __restrict__ W_ea, const float* __restrict__ b_ea,
               const float* __restrict__ W_ih, const float* __restrict__ b_ih,
               float* __restrict__ gi, int row_base)
{
    __shared__ __align__(16) float Et[EAIN][36];   // E transposed [k][r], pad 36 for banks+align
    __shared__ __align__(16) float eat[HIDD][36];  // ea transposed [k][r]

    const int tid = threadIdx.x;
    const int rel0 = blockIdx.x * GI_ROWS;         // chunk-relative row of r=0
    const int rg0  = row_base + rel0;              // global row

    // stage E = concat(embed, action), transposed
    for (int idx = tid; idx < GI_ROWS * EAIN; idx += GI_THREADS) {
        int r = idx / EAIN, k = idx % EAIN;
        size_t rg = (size_t)(rg0 + r);
        float v = (k < EMBED) ? embed[rg * EMBED + k]
                              : action[rg * ACTD + (k - EMBED)];
        Et[k][r] = v;
    }
    __syncthreads();

    // ea: thread c (<200) computes column c for all 32 rows
    if (tid < HIDD) {
        const int c = tid;
        float acc[GI_ROWS];
        const float bv = b_ea[c];
        #pragma unroll
        for (int r = 0; r < GI_ROWS; r++) acc[r] = bv;
        for (int k = 0; k < EAIN; k++) {
            float w = W_ea[k * HIDD + c];
            #pragma unroll
            for (int r4 = 0; r4 < GI_ROWS / 4; r4++) {
                const float4 h4 = *(const float4*)&Et[k][r4 * 4];
                acc[r4 * 4 + 0] += w * h4.x;
                acc[r4 * 4 + 1] += w * h4.y;
                acc[r4 * 4 + 2] += w * h4.z;
                acc[r4 * 4 + 3] += w * h4.w;
            }
        }
        #pragma unroll
        for (int r = 0; r < GI_ROWS; r++) eat[c][r] = eluf(acc[r]);
    }
    __syncthreads();

    // gi: thread c (<600) computes column c for all 32 rows
    if (tid < G3) {
        const int c = tid;
        float acc[GI_ROWS];
        const float bv = b_ih[c];
        #pragma unroll
        for (int r = 0; r < GI_ROWS; r++) acc[r] = bv;
        for (int k = 0; k < HIDD; k++) {
            float w = W_ih[k * G3 + c];
            #pragma unroll
            for (int r4 = 0; r4 < GI_ROWS / 4; r4++) {
                const float4 h4 = *(const float4*)&eat[k][r4 * 4];
                acc[r4 * 4 + 0] += w * h4.x;
                acc[r4 * 4 + 1] += w * h4.y;
                acc[r4 * 4 + 2] += w * h4.z;
                acc[r4 * 4 + 3] += w * h4.w;
            }
        }
        #pragma unroll
        for (int r = 0; r < GI_ROWS; r++)
            gi[(size_t)(rel0 + r) * G3 + c] = acc[r];
    }
}

// ---------- phase B: sequential GRU recurrence, W_hh register-resident ----------
#define RB_THREADS 640
#define NB 2

__global__ __launch_bounds__(RB_THREADS, 1)
void recur_kernel(const float* __restrict__ gi, const float* __restrict__ W_hh,
                  const float* __restrict__ b_hh, const float* __restrict__ in_state,
                  const unsigned char* __restrict__ reset_raw, const int* __restrict__ flags,
                  float* __restrict__ out_states, float* __restrict__ h_buf,
                  int t0, int t1, int first)
{
    __shared__ __align__(16) float h_s[NB][MEM];
    __shared__ __align__(16) float gh_s[NB][G3];

    const int tid = threadIdx.x;
    const int bg0 = blockIdx.x * NB;
    const int mode = flags[0];

    // thread j<600 owns column j of W_hh in registers (200 VGPRs)
    float wcol[MEM];
    float bh = 0.f;
    if (tid < G3) {
        bh = b_hh[tid];
        #pragma unroll
        for (int k = 0; k < MEM; k++) wcol[k] = W_hh[k * G3 + tid];
    }

    // init h (reset[t0] already applied if resuming from h_buf)
    if (tid < NB * MEM) {
        int b = tid / MEM, m = tid % MEM;
        int bg = bg0 + b;
        float h;
        if (first) {
            h = in_state[bg * MEM + m];
            if (resetval(reset_raw, mode, 0 * B_ + bg)) h = 0.f;
        } else {
            h = h_buf[bg * MEM + m];
        }
        h_s[b][m] = h;
    }
    __syncthreads();

    for (int t = t0; t < t1; ++t) {
        // gh = h @ W_hh + b_hh for both batch rows
        if (tid < G3) {
            float a0a = bh, a0b = 0.f, a1a = 0.f, a1b = 0.f;
            #pragma unroll
            for (int k4 = 0; k4 < MEM / 4; k4++) {
                const float4 h0 = *(const float4*)&h_s[0][k4 * 4];
                const float4 h1 = *(const float4*)&h_s[1][k4 * 4];
                a0a += wcol[k4 * 4 + 0] * h0.x;
                a0b += wcol[k4 * 4 + 1] * h0.y;
                a0a += wcol[k4 * 4 + 2] * h0.z;
                a0b += wcol[k4 * 4 + 3] * h0.w;
                a1a += wcol[k4 * 4 + 0] * h1.x;
                a1b += wcol[k4 * 4 + 1] * h1.y;
                a1a += wcol[k4 * 4 + 2] * h1.z;
                a1b += wcol[k4 * 4 + 3] * h1.w;
            }
            gh_s[0][tid] = a0a + a0b;
            gh_s[1][tid] = bh + a1a + a1b;
        }
        __syncthreads();

        // gates + state update + output
        if (tid < NB * MEM) {
            int b = tid / MEM, m = tid % MEM;
            int bg = bg0 + b;
            const float* gir = gi + ((size_t)(t - t0) * B_ + bg) * G3;
            float gi_r = gir[m], gi_z = gir[MEM + m], gi_n = gir[2 * MEM + m];
            float gh_r = gh_s[b][m], gh_z = gh_s[b][MEM + m], gh_n = gh_s[b][2 * MEM + m];
            float rg = sigmf(gi_r + gh_r);
            float zg = sigmf(gi_z + gh_z);
            float x  = gi_n + rg * gh_n;
            x = fminf(fmaxf(x, -30.f), 30.f);
            float e2 = __expf(2.f * x);
            float ng = (e2 - 1.f) / (e2 + 1.f);
            float h_old = h_s[b][m];
            float hn = (1.f - zg) * ng + zg * h_old;
            out_states[((size_t)t * B_ + bg) * MEM + m] = hn;
            // pre-apply next step's reset
            if (t + 1 < T_) {
                if (resetval(reset_raw, mode, (t + 1) * B_ + bg)) hn = 0.f;
            }
            h_s[b][m] = hn;
        }
        __syncthreads();
    }

    // persist h for next chunk
    if (tid < NB * MEM) {
        int b = tid / MEM, m = tid % MEM;
        h_buf[(bg0 + b) * MEM + m] = h_s[b][m];
    }
}

// ---------- phase C: post MLP over all states (parallel) ----------
#define PC_THREADS 256
#define PC_ROWS 32

__global__ __launch_bounds__(PC_THREADS, 1)
void post_kernel(const float* __restrict__ states, const float* __restrict__ Wp1,
                 const float* __restrict__ bp1, const float* __restrict__ Wp2,
                 const float* __restrict__ bp2, float* __restrict__ posts)
{
    __shared__ __align__(16) float ht[MEM][36];
    __shared__ __align__(16) float mt[MEM][36];

    const int tid = threadIdx.x;
    const size_t rg0 = (size_t)blockIdx.x * PC_ROWS;

    for (int idx = tid; idx < PC_ROWS * MEM; idx += PC_THREADS) {
        int r = idx / MEM, k = idx % MEM;
        ht[k][r] = states[(rg0 + r) * MEM + k];
    }
    __syncthreads();

    // mid = elu(h@Wp1+bp1): thread c<200, 32 rows
    if (tid < MEM) {
        const int c = tid;
        float acc[PC_ROWS];
        const float bv = bp1[c];
        #pragma unroll
        for (int r = 0; r < PC_ROWS; r++) acc[r] = bv;
        for (int k = 0; k < MEM; k++) {
            float w = Wp1[k * MEM + c];
            #pragma unroll
            for (int r4 = 0; r4 < PC_ROWS / 4; r4++) {
                const float4 h4 = *(const float4*)&ht[k][r4 * 4];
                acc[r4 * 4 + 0] += w * h4.x;
                acc[r4 * 4 + 1] += w * h4.y;
                acc[r4 * 4 + 2] += w * h4.z;
                acc[r4 * 4 + 3] += w * h4.w;
            }
        }
        #pragma unroll
        for (int r = 0; r < PC_ROWS; r++) mt[c][r] = eluf(acc[r]);
    }
    __syncthreads();

    // post = mid@Wp2+bp2, then mean/std transform: thread = (c<60, quarter q<4), 8 rows each
    if (tid < 240) {
        const int c = tid % 60;
        const int q = tid / 60;
        float acc[8];
        const float bv = bp2[c];
        #pragma unroll
        for (int r = 0; r < 8; r++) acc[r] = bv;
        for (int k = 0; k < MEM; k++) {
            float w = Wp2[k * 60 + c];
            const float4 a = *(const float4*)&mt[k][q * 8 + 0];
            const float4 b = *(const float4*)&mt[k][q * 8 + 4];
            acc[0] += w * a.x; acc[1] += w * a.y; acc[2] += w * a.z; acc[3] += w * a.w;
            acc[4] += w * b.x; acc[5] += w * b.y; acc[6] += w * b.z; acc[7] += w * b.w;
        }
        #pragma unroll
        for (int r8 = 0; r8 < 8; r8++) {
            size_t rg = rg0 + q * 8 + r8;
            float v = acc[r8];
            posts[rg * 60 + c] = (c < 30) ? v : (splusf(v) + 0.1f);
        }
    }
}

// ---------- sample = mean + std*noise from posts[T-1] ----------
__global__ void sample_kernel(const float* __restrict__ posts_last,
                              const float* __restrict__ noise, float* __restrict__ out)
{
    int idx = blockIdx.x * blockDim.x + threadIdx.x;
    if (idx < B_ * STOCH) {
        int b = idx / STOCH, s = idx % STOCH;
        float mean = posts_last[b * 60 + s];
        float stdv = posts_last[b * 60 + 30 + s];
        out[idx] = mean + stdv * noise[idx];
    }
}

extern "C" void kernel_launch(void* const* d_in, const int* in_sizes, int n_in,
                              void* d_out, int out_size, void* d_ws, size_t ws_size,
                              hipStream_t stream)
{
    const float* embed   = (const float*)d_in[0];
    const float* action  = (const float*)d_in[1];
    const unsigned char* reset = (const unsigned char*)d_in[2];
    const float* in_state = (const float*)d_in[3];
    const float* noise   = (const float*)d_in[4];
    const float* W_ea = (const float*)d_in[5];
    const float* b_ea = (const float*)d_in[6];
    const float* W_ih = (const float*)d_in[7];
    const float* b_ih = (const float*)d_in[8];
    const float* W_hh = (const float*)d_in[9];
    const float* b_hh = (const float*)d_in[10];
    const float* Wp1  = (const float*)d_in[11];
    const float* bp1  = (const float*)d_in[12];
    const float* Wp2  = (const float*)d_in[13];
    const float* bp2  = (const float*)d_in[14];

    float* out_sample = (float*)d_out;
    float* out_states = out_sample + (size_t)B_ * STOCH;
    float* out_posts  = out_states + (size_t)T_ * B_ * MEM;

    char* ws = (char*)d_ws;
    int*   flags = (int*)ws;
    float* h_buf = (float*)(ws + 256);
    float* gi_buf = (float*)(ws + 256 + (size_t)B_ * MEM * 4);

    const size_t fixed = 256 + (size_t)B_ * MEM * 4;
    const size_t per_t = (size_t)B_ * G3 * 4;            // 1.2288 MB per timestep
    size_t avail = (ws_size > fixed) ? (ws_size - fixed) : 0;
    int maxT = (int)(avail / per_t);
    int chunkT = 1;
    while (chunkT * 2 <= maxT && chunkT < T_) chunkT *= 2;  // largest pow2 divisor of 256 that fits

    detect_kernel<<<1, 1024, 0, stream>>>(reset, T_ * B_, flags);

    for (int t0 = 0; t0 < T_; t0 += chunkT) {
        int rows = chunkT * B_;
        gi_kernel<<<rows / GI_ROWS, GI_THREADS, 0, stream>>>(
            embed, action, W_ea, b_ea, W_ih, b_ih, gi_buf, t0 * B_);
        recur_kernel<<<B_ / NB, RB_THREADS, 0, stream>>>(
            gi_buf, W_hh, b_hh, in_state, reset, flags,
            out_states, h_buf, t0, t0 + chunkT, (t0 == 0) ? 1 : 0);
    }

    post_kernel<<<(T_ * B_) / PC_ROWS, PC_THREADS, 0, stream>>>(
        out_states, Wp1, bp1, Wp2, bp2, out_posts);

    sample_kernel<<<(B_ * STOCH + 255) / 256, 256, 0, stream>>>(
        out_posts + (size_t)(T_ - 1) * B_ * 60, noise, out_sample);
}

// Round 3
// 1492.597 us; speedup vs baseline: 2.8414x; 2.8414x over previous
//
#include <hip/hip_runtime.h>
#include <math.h>

#define EMBED 256
#define ACTD  7
#define MEM   200
#define STOCH 30
#define HIDD  200
#define T_    256
#define B_    512
#define EAIN  263      // EMBED + ACTD
#define G3    600      // 3*MEM
#define K2EA  132      // ceil(EAIN/2)
#define K2IH  100      // HIDD/2
#define RP    36       // padded row length (dwords) for LDS tiles

typedef unsigned int uint32;
typedef _Float16 h2v __attribute__((ext_vector_type(2)));

// ---------- math helpers ----------
__device__ __forceinline__ float eluf(float x)  { return x > 0.f ? x : expm1f(x); }
__device__ __forceinline__ float sigmf(float x) { return 1.f / (1.f + __expf(-x)); }
__device__ __forceinline__ float splusf(float x){ return fmaxf(x, 0.f) + log1pf(__expf(-fabsf(x))); }

__device__ __forceinline__ uint32 packh2(float a, float b) {
#if __has_builtin(__builtin_amdgcn_cvt_pkrtz)
    auto h = __builtin_amdgcn_cvt_pkrtz(a, b);   // __fp16 ext_vector(2)
    return __builtin_bit_cast(uint32, h);
#else
    h2v h; h.x = (_Float16)a; h.y = (_Float16)b;
    return __builtin_bit_cast(uint32, h);
#endif
}

__device__ __forceinline__ float dot2f(uint32 a, uint32 b, float acc) {
#if __has_builtin(__builtin_amdgcn_fdot2)
    return __builtin_amdgcn_fdot2(__builtin_bit_cast(h2v, a),
                                  __builtin_bit_cast(h2v, b), acc, false);
#else
    h2v ha = __builtin_bit_cast(h2v, a), hb = __builtin_bit_cast(h2v, b);
    return acc + (float)ha.x * (float)hb.x + (float)ha.y * (float)hb.y;
#endif
}

// ---------- reset dtype detection ----------
__global__ void detect_kernel(const unsigned char* __restrict__ p, int n, int* __restrict__ flags)
{
    __shared__ int s_mis, s_gt1;
    if (threadIdx.x == 0) { s_mis = 0; s_gt1 = 0; }
    __syncthreads();
    int mis = 0, gt1 = 0;
    for (int i = threadIdx.x; i < n; i += blockDim.x) {
        unsigned char v = p[i];
        if (v) {
            if (i & 3) mis = 1;
            if (v > 1) gt1 = 1;
        }
    }
    if (mis) atomicOr(&s_mis, 1);
    if (gt1) atomicOr(&s_gt1, 1);
    __syncthreads();
    if (threadIdx.x == 0) flags[0] = s_mis ? (s_gt1 ? 2 : 1) : 0;
}

__device__ __forceinline__ bool resetval(const unsigned char* __restrict__ p, int mode, int idx)
{
    if (mode == 0) return ((const int*)p)[idx] != 0;
    if (mode == 1) return p[idx] != 0;
    return ((const float*)p)[idx] != 0.f;
}

// ---------- weight packing: src[K][C] f32 -> dst[ceil(K/2)][C] f16x2 ----------
__global__ void pack_kernel(const float* __restrict__ src, uint32* __restrict__ dst, int K, int C)
{
    int idx = blockIdx.x * blockDim.x + threadIdx.x;
    int K2 = (K + 1) >> 1;
    if (idx < K2 * C) {
        int k2 = idx / C, c = idx % C;
        float a = src[(size_t)(2 * k2) * C + c];
        float b = (2 * k2 + 1 < K) ? src[(size_t)(2 * k2 + 1) * C + c] : 0.f;
        dst[idx] = packh2(a, b);
    }
}

// ---------- phase A: gi = elu([e,a]@W_ea+b_ea)@W_ih + b_ih ----------
#define GI_ROWS 32
#define GI_THREADS 640

__global__ __launch_bounds__(GI_THREADS)
void gi2_kernel(const float* __restrict__ embed, const float* __restrict__ action,
                const uint32* __restrict__ Wea_pk, const float* __restrict__ b_ea,
                const uint32* __restrict__ Wih_pk, const float* __restrict__ b_ih,
                float* __restrict__ gi, int row_base)
{
    __shared__ __align__(16) uint32 Epk[K2EA][RP];   // packed E, [k2][r]
    __shared__ __align__(16) uint32 eapk[K2IH][RP];  // packed elu(ea), [c2][r]

    const int tid = threadIdx.x;
    const int rel0 = blockIdx.x * GI_ROWS;
    const int rg0  = row_base + rel0;

    // stage E = concat(embed, action) as packed f16 pairs over k
    for (int idx = tid; idx < GI_ROWS * K2EA; idx += GI_THREADS) {
        int r = idx / K2EA, k2 = idx % K2EA;
        size_t rg = (size_t)(rg0 + r);
        float a, b;
        if (k2 < EMBED / 2) {
            const float2 v = *(const float2*)&embed[rg * EMBED + 2 * k2];
            a = v.x; b = v.y;
        } else {
            int k = 2 * k2 - EMBED;                 // 0..6 in action
            a = action[rg * ACTD + k];
            b = (k + 1 < ACTD) ? action[rg * ACTD + k + 1] : 0.f;
        }
        Epk[k2][r] = packh2(a, b);
    }
    __syncthreads();

    // ea phase: 400 threads, (c<200, g<2), 16 rows each
    if (tid < 400) {
        const int c = tid % 200;
        const int g = tid / 200;
        float acc[16];
        const float bv = b_ea[c];
        #pragma unroll
        for (int r = 0; r < 16; r++) acc[r] = bv;
        for (int k2 = 0; k2 < K2EA; k2++) {
            uint32 w = Wea_pk[k2 * 200 + c];
            #pragma unroll
            for (int q = 0; q < 4; q++) {
                const uint4 e4 = *(const uint4*)&Epk[k2][g * 16 + q * 4];
                acc[q * 4 + 0] = dot2f(w, e4.x, acc[q * 4 + 0]);
                acc[q * 4 + 1] = dot2f(w, e4.y, acc[q * 4 + 1]);
                acc[q * 4 + 2] = dot2f(w, e4.z, acc[q * 4 + 2]);
                acc[q * 4 + 3] = dot2f(w, e4.w, acc[q * 4 + 3]);
            }
        }
        // elu, then pack pairs over c via lane shuffle (lane parity == c parity)
        uint32 packed[16];
        #pragma unroll
        for (int r = 0; r < 16; r++) {
            float v = eluf(acc[r]);
            float p = __shfl_xor(v, 1);
            packed[r] = packh2(v, p);
        }
        if ((c & 1) == 0) {
            #pragma unroll
            for (int q = 0; q < 4; q++) {
                uint4 u;
                u.x = packed[q * 4 + 0]; u.y = packed[q * 4 + 1];
                u.z = packed[q * 4 + 2]; u.w = packed[q * 4 + 3];
                *(uint4*)&eapk[c >> 1][g * 16 + q * 4] = u;
            }
        }
    }
    __syncthreads();

    // gi phase: 600 threads, col c, 32 rows each
    if (tid < G3) {
        const int c = tid;
        float acc[GI_ROWS];
        const float bv = b_ih[c];
        #pragma unroll
        for (int r = 0; r < GI_ROWS; r++) acc[r] = bv;
        for (int k2 = 0; k2 < K2IH; k2++) {
            uint32 w = Wih_pk[k2 * G3 + c];
            #pragma unroll
            for (int q = 0; q < 8; q++) {
                const uint4 e4 = *(const uint4*)&eapk[k2][q * 4];
                acc[q * 4 + 0] = dot2f(w, e4.x, acc[q * 4 + 0]);
                acc[q * 4 + 1] = dot2f(w, e4.y, acc[q * 4 + 1]);
                acc[q * 4 + 2] = dot2f(w, e4.z, acc[q * 4 + 2]);
                acc[q * 4 + 3] = dot2f(w, e4.w, acc[q * 4 + 3]);
            }
        }
        #pragma unroll
        for (int r = 0; r < GI_ROWS; r++)
            gi[(size_t)(rel0 + r) * G3 + c] = acc[r];
    }
}

// ---------- phase B: sequential GRU recurrence, packed-f16 W_hh in VGPRs ----------
#define RB_THREADS 640
#define NB 2

__global__ __launch_bounds__(RB_THREADS, 2)
void recur2_kernel(const float* __restrict__ gi, const uint32* __restrict__ Whh_pk,
                   const float* __restrict__ b_hh, const float* __restrict__ in_state,
                   const unsigned char* __restrict__ reset_raw, const int* __restrict__ flags,
                   float* __restrict__ out_states, float* __restrict__ h_buf,
                   int t0, int t1, int first)
{
    __shared__ __align__(16) uint32 hpk[NB][K2IH];  // packed f16 h, 100 dwords/row
    __shared__ __align__(16) float  gh_s[NB][G3];

    const int tid = threadIdx.x;
    const int bg0 = blockIdx.x * NB;
    const int mode = flags[0];

    // thread j<600 owns packed column j of W_hh: 100 VGPRs
    uint32 wpk[K2IH];
    float bh = 0.f;
    if (tid < G3) {
        bh = b_hh[tid];
        #pragma unroll
        for (int j = 0; j < K2IH; j++) wpk[j] = Whh_pk[j * G3 + tid];
    }

    const int b  = (tid < NB * MEM) ? tid / MEM : 0;
    const int m  = (tid < NB * MEM) ? tid % MEM : 0;
    const int bg = bg0 + b;
    float h_old = 0.f;

    if (tid < NB * MEM) {
        float h;
        if (first) {
            h = in_state[bg * MEM + m];
            if (resetval(reset_raw, mode, bg)) h = 0.f;
        } else {
            h = h_buf[bg * MEM + m];
        }
        h_old = h;
        float p = __shfl_xor(h, 1);
        if ((m & 1) == 0) hpk[b][m >> 1] = packh2(h, p);
    }
    __syncthreads();

    for (int t = t0; t < t1; ++t) {
        // prefetch this step's gi + next reset (completes under the dot loop)
        float gr = 0.f, gz = 0.f, gn = 0.f;
        bool rnext = false;
        if (tid < NB * MEM) {
            const float* gir = gi + ((size_t)(t - t0) * B_ + bg) * G3;
            gr = gir[m]; gz = gir[MEM + m]; gn = gir[2 * MEM + m];
            if (t + 1 < T_) rnext = resetval(reset_raw, mode, (t + 1) * B_ + bg);
        }

        // gh = h @ W_hh + b_hh, both batch rows, via f16 dot2
        if (tid < G3) {
            float a0 = 0.f, a1 = 0.f;
            #pragma unroll
            for (int j4 = 0; j4 < K2IH / 4; j4++) {
                const uint4 p0 = *(const uint4*)&hpk[0][j4 * 4];
                const uint4 p1 = *(const uint4*)&hpk[1][j4 * 4];
                a0 = dot2f(wpk[j4 * 4 + 0], p0.x, a0);
                a0 = dot2f(wpk[j4 * 4 + 1], p0.y, a0);
                a0 = dot2f(wpk[j4 * 4 + 2], p0.z, a0);
                a0 = dot2f(wpk[j4 * 4 + 3], p0.w, a0);
                a1 = dot2f(wpk[j4 * 4 + 0], p1.x, a1);
                a1 = dot2f(wpk[j4 * 4 + 1], p1.y, a1);
                a1 = dot2f(wpk[j4 * 4 + 2], p1.z, a1);
                a1 = dot2f(wpk[j4 * 4 + 3], p1.w, a1);
            }
            gh_s[0][tid] = a0 + bh;
            gh_s[1][tid] = a1 + bh;
        }
        __syncthreads();

        // gates + state update
        if (tid < NB * MEM) {
            float gh_r = gh_s[b][m], gh_z = gh_s[b][MEM + m], gh_n = gh_s[b][2 * MEM + m];
            float rg = sigmf(gr + gh_r);
            float zg = sigmf(gz + gh_z);
            float x  = gn + rg * gh_n;
            x = fminf(fmaxf(x, -30.f), 30.f);
            float e2 = __expf(2.f * x);
            float ng = (e2 - 1.f) / (e2 + 1.f);
            float hn = (1.f - zg) * ng + zg * h_old;
            out_states[((size_t)t * B_ + bg) * MEM + m] = hn;
            if (rnext) hn = 0.f;
            h_old = hn;
            float p = __shfl_xor(hn, 1);
            if ((m & 1) == 0) hpk[b][m >> 1] = packh2(hn, p);
        }
        __syncthreads();
    }

    if (tid < NB * MEM) h_buf[bg * MEM + m] = h_old;
}

// ---------- phase C: post MLP over all states ----------
#define PC_THREADS 256
#define PC_ROWS 32

__global__ __launch_bounds__(PC_THREADS)
void post2_kernel(const float* __restrict__ states, const uint32* __restrict__ Wp1_pk,
                  const float* __restrict__ bp1, const uint32* __restrict__ Wp2_pk,
                  const float* __restrict__ bp2, float* __restrict__ posts)
{
    __shared__ __align__(16) uint32 hp[K2IH][RP];   // packed states [k2][r]
    __shared__ __align__(16) uint32 mp[K2IH][RP];   // packed elu(mid) [c2][r]

    const int tid = threadIdx.x;
    const size_t rg0 = (size_t)blockIdx.x * PC_ROWS;

    for (int idx = tid; idx < PC_ROWS * K2IH; idx += PC_THREADS) {
        int r = idx / K2IH, k2 = idx % K2IH;
        const float2 v = *(const float2*)&states[(rg0 + r) * MEM + 2 * k2];
        hp[k2][r] = packh2(v.x, v.y);
    }
    __syncthreads();

    // mid = elu(h@Wp1+bp1): 200 threads, 32 rows
    if (tid < MEM) {
        const int c = tid;
        float acc[PC_ROWS];
        const float bv = bp1[c];
        #pragma unroll
        for (int r = 0; r < PC_ROWS; r++) acc[r] = bv;
        for (int k2 = 0; k2 < K2IH; k2++) {
            uint32 w = Wp1_pk[k2 * MEM + c];
            #pragma unroll
            for (int q = 0; q < 8; q++) {
                const uint4 e4 = *(const uint4*)&hp[k2][q * 4];
                acc[q * 4 + 0] = dot2f(w, e4.x, acc[q * 4 + 0]);
                acc[q * 4 + 1] = dot2f(w, e4.y, acc[q * 4 + 1]);
                acc[q * 4 + 2] = dot2f(w, e4.z, acc[q * 4 + 2]);
                acc[q * 4 + 3] = dot2f(w, e4.w, acc[q * 4 + 3]);
            }
        }
        uint32 packed[PC_ROWS];
        #pragma unroll
        for (int r = 0; r < PC_ROWS; r++) {
            float v = eluf(acc[r]);
            float p = __shfl_xor(v, 1);
            packed[r] = packh2(v, p);
        }
        if ((c & 1) == 0) {
            #pragma unroll
            for (int q = 0; q < 8; q++) {
                uint4 u;
                u.x = packed[q * 4 + 0]; u.y = packed[q * 4 + 1];
                u.z = packed[q * 4 + 2]; u.w = packed[q * 4 + 3];
                *(uint4*)&mp[c >> 1][q * 4] = u;
            }
        }
    }
    __syncthreads();

    // post = mid@Wp2+bp2 (+ mean/std transform): 240 threads = (c<60, q<4), 8 rows each
    if (tid < 240) {
        const int c = tid % 60;
        const int q = tid / 60;
        float acc[8];
        const float bv = bp2[c];
        #pragma unroll
        for (int r = 0; r < 8; r++) acc[r] = bv;
        for (int k2 = 0; k2 < K2IH; k2++) {
            uint32 w = Wp2_pk[k2 * 60 + c];
            const uint4 a4 = *(const uint4*)&mp[k2][q * 8 + 0];
            const uint4 b4 = *(const uint4*)&mp[k2][q * 8 + 4];
            acc[0] = dot2f(w, a4.x, acc[0]);
            acc[1] = dot2f(w, a4.y, acc[1]);
            acc[2] = dot2f(w, a4.z, acc[2]);
            acc[3] = dot2f(w, a4.w, acc[3]);
            acc[4] = dot2f(w, b4.x, acc[4]);
            acc[5] = dot2f(w, b4.y, acc[5]);
            acc[6] = dot2f(w, b4.z, acc[6]);
            acc[7] = dot2f(w, b4.w, acc[7]);
        }
        #pragma unroll
        for (int r8 = 0; r8 < 8; r8++) {
            size_t rg = rg0 + q * 8 + r8;
            float v = acc[r8];
            posts[rg * 60 + c] = (c < 30) ? v : (splusf(v) + 0.1f);
        }
    }
}

// ---------- sample = mean + std*noise from posts[T-1] ----------
__global__ void sample_kernel(const float* __restrict__ posts_last,
                              const float* __restrict__ noise, float* __restrict__ out)
{
    int idx = blockIdx.x * blockDim.x + threadIdx.x;
    if (idx < B_ * STOCH) {
        int b = idx / STOCH, s = idx % STOCH;
        float mean = posts_last[b * 60 + s];
        float stdv = posts_last[b * 60 + 30 + s];
        out[idx] = mean + stdv * noise[idx];
    }
}

extern "C" void kernel_launch(void* const* d_in, const int* in_sizes, int n_in,
                              void* d_out, int out_size, void* d_ws, size_t ws_size,
                              hipStream_t stream)
{
    const float* embed   = (const float*)d_in[0];
    const float* action  = (const float*)d_in[1];
    const unsigned char* reset = (const unsigned char*)d_in[2];
    const float* in_state = (const float*)d_in[3];
    const float* noise   = (const float*)d_in[4];
    const float* W_ea = (const float*)d_in[5];
    const float* b_ea = (const float*)d_in[6];
    const float* W_ih = (const float*)d_in[7];
    const float* b_ih = (const float*)d_in[8];
    const float* W_hh = (const float*)d_in[9];
    const float* b_hh = (const float*)d_in[10];
    const float* Wp1  = (const float*)d_in[11];
    const float* bp1  = (const float*)d_in[12];
    const float* Wp2  = (const float*)d_in[13];
    const float* bp2  = (const float*)d_in[14];

    float* out_sample = (float*)d_out;
    float* out_states = out_sample + (size_t)B_ * STOCH;
    float* out_posts  = out_states + (size_t)T_ * B_ * MEM;

    char* ws = (char*)d_ws;
    size_t off = 0;
    int*    flags  = (int*)(ws + off);      off += 256;
    float*  h_buf  = (float*)(ws + off);    off += (size_t)B_ * MEM * 4;        // 409600
    uint32* Wea_pk = (uint32*)(ws + off);   off += (size_t)K2EA * 200 * 4;      // 105600
    uint32* Wih_pk = (uint32*)(ws + off);   off += (size_t)K2IH * G3 * 4;       // 240000
    uint32* Whh_pk = (uint32*)(ws + off);   off += (size_t)K2IH * G3 * 4;       // 240000
    uint32* Wp1_pk = (uint32*)(ws + off);   off += (size_t)K2IH * MEM * 4;      // 80000
    uint32* Wp2_pk = (uint32*)(ws + off);   off += (size_t)K2IH * 60 * 4;       // 24000
    float*  gi_buf = (float*)(ws + off);

    const size_t per_t = (size_t)B_ * G3 * 4;
    size_t avail = (ws_size > off) ? (ws_size - off) : 0;
    int maxT = (int)(avail / per_t);
    int chunkT = 1;
    while (chunkT * 2 <= maxT && chunkT < T_) chunkT *= 2;

    detect_kernel<<<1, 1024, 0, stream>>>(reset, T_ * B_, flags);
    pack_kernel<<<(K2EA * 200 + 255) / 256, 256, 0, stream>>>(W_ea, Wea_pk, EAIN, 200);
    pack_kernel<<<(K2IH * G3 + 255) / 256, 256, 0, stream>>>(W_ih, Wih_pk, HIDD, G3);
    pack_kernel<<<(K2IH * G3 + 255) / 256, 256, 0, stream>>>(W_hh, Whh_pk, MEM, G3);
    pack_kernel<<<(K2IH * MEM + 255) / 256, 256, 0, stream>>>(Wp1, Wp1_pk, MEM, MEM);
    pack_kernel<<<(K2IH * 60 + 255) / 256, 256, 0, stream>>>(Wp2, Wp2_pk, MEM, 60);

    for (int t0 = 0; t0 < T_; t0 += chunkT) {
        int rows = chunkT * B_;
        gi2_kernel<<<rows / GI_ROWS, GI_THREADS, 0, stream>>>(
            embed, action, Wea_pk, b_ea, Wih_pk, b_ih, gi_buf, t0 * B_);
        recur2_kernel<<<B_ / NB, RB_THREADS, 0, stream>>>(
            gi_buf, Whh_pk, b_hh, in_state, reset, flags,
            out_states, h_buf, t0, t0 + chunkT, (t0 == 0) ? 1 : 0);
    }

    post2_kernel<<<(T_ * B_) / PC_ROWS, PC_THREADS, 0, stream>>>(
        out_states, Wp1_pk, bp1, Wp2_pk, bp2, out_posts);

    sample_kernel<<<(B_ * STOCH + 255) / 256, 256, 0, stream>>>(
        out_posts + (size_t)(T_ - 1) * B_ * 60, noise, out_sample);
}